// Round 5
// baseline (438.914 us; speedup 1.0000x reference)
//
#include <hip/hip_runtime.h>

#define T_SEQ 4096
#define H_NUM 12
#define HD    64
#define C_DIM 768
#define N_QKV 2304
#define HT    (T_SEQ * HD)   // per-head elements = 262144

typedef float    f32x4 __attribute__((ext_vector_type(4)));
typedef _Float16 half8 __attribute__((ext_vector_type(8)));
typedef _Float16 half4 __attribute__((ext_vector_type(4)));

// async global->LDS, 16B/lane, dest = wave-uniform base + lane*16
#define GLDS(gp, lp) __builtin_amdgcn_global_load_lds( \
    (const __attribute__((address_space(1))) void*)(gp), \
    (__attribute__((address_space(3))) void*)(lp), 16, 0, 0)

// ---------------------------------------------------------------------------
// split x (fp32) -> xhi + xlo (f16 planes)
// ---------------------------------------------------------------------------
__global__ __launch_bounds__(256) void split_x_kernel(
    const float* __restrict__ x, _Float16* __restrict__ xh,
    _Float16* __restrict__ xl, int n4)
{
    const int i = blockIdx.x * 256 + threadIdx.x;
    if (i >= n4) return;
    const float4 v = ((const float4*)x)[i];
    const float vv[4] = {v.x, v.y, v.z, v.w};
    half4 h, l;
    #pragma unroll
    for (int j = 0; j < 4; ++j) {
        const _Float16 hh = (_Float16)vv[j];
        h[j] = hh;
        l[j] = (_Float16)(vv[j] - (float)hh);
    }
    ((half4*)xh)[i] = h;
    ((half4*)xl)[i] = l;
}

// ---------------------------------------------------------------------------
// transpose+split w_attn [768][2304] -> wthi/wtlo [2304][768] (f16)
// ---------------------------------------------------------------------------
__global__ __launch_bounds__(256) void split_wt_kernel(
    const float* __restrict__ W, _Float16* __restrict__ wth,
    _Float16* __restrict__ wtl)
{
    __shared__ float Ws[64][65];
    const int tid = threadIdx.x;
    const int n0 = blockIdx.x * 64, k0 = blockIdx.y * 64;
    const int lr = tid >> 4, lc = (tid & 15) << 2;
    #pragma unroll
    for (int i = 0; i < 4; ++i) {
        const float4 v = *(const float4*)(W + (size_t)(k0 + lr + i * 16) * N_QKV + n0 + lc);
        Ws[lr + i * 16][lc + 0] = v.x; Ws[lr + i * 16][lc + 1] = v.y;
        Ws[lr + i * 16][lc + 2] = v.z; Ws[lr + i * 16][lc + 3] = v.w;
    }
    __syncthreads();
    const int n = tid >> 2, ks = (tid & 3) << 4;
    half8 h0, h1, l0, l1;
    #pragma unroll
    for (int j = 0; j < 8; ++j) {
        const float v = Ws[ks + j][n];
        const _Float16 hh = (_Float16)v;
        h0[j] = hh; l0[j] = (_Float16)(v - (float)hh);
    }
    #pragma unroll
    for (int j = 0; j < 8; ++j) {
        const float v = Ws[ks + 8 + j][n];
        const _Float16 hh = (_Float16)v;
        h1[j] = hh; l1[j] = (_Float16)(v - (float)hh);
    }
    const size_t dst = (size_t)(n0 + n) * C_DIM + k0 + ks;
    *(half8*)(wth + dst) = h0; *(half8*)(wth + dst + 8) = h1;
    *(half8*)(wtl + dst) = l0; *(half8*)(wtl + dst + 8) = l1;
}

// ---------------------------------------------------------------------------
// QKV GEMM via split-f16 MFMA (AhBh + AhBl + AlBh), 128m x 64n tile, BK=64.
// Epilogue: bias + l2norm + hi/lo split (q,k) or bias + V transpose (v).
// ---------------------------------------------------------------------------
__global__ __launch_bounds__(256) void gemm_qkv_kernel(
    const _Float16* __restrict__ xh, const _Float16* __restrict__ xl,
    const _Float16* __restrict__ wth, const _Float16* __restrict__ wtl,
    const float* __restrict__ bias,
    _Float16* __restrict__ qhi, _Float16* __restrict__ qlo,
    _Float16* __restrict__ khi, _Float16* __restrict__ klo,
    _Float16* __restrict__ vt)
{
    __shared__ __align__(16) _Float16 AH[128 * 64];
    __shared__ __align__(16) _Float16 AL[128 * 64];
    __shared__ __align__(16) _Float16 BH[64 * 64];
    __shared__ __align__(16) _Float16 BL[64 * 64];
    const int tid = threadIdx.x;
    const int wv = tid >> 6, lane = tid & 63;
    const int fm = lane & 15, fg = lane >> 4;
    const int lrow = lane >> 3;
    const int lcs  = (lane & 7) ^ (lrow & 7);
    const int bx = blockIdx.x;
    const int m0 = blockIdx.y * 128;

    auto dma_chunk = [&](int c) {
        const int kc0 = c * 64;
        #pragma unroll
        for (int i = 0; i < 12; ++i) {
            const int qidx = wv * 12 + i;
            if (qidx < 16) {
                const int rg = qidx;
                GLDS(xh + (size_t)(m0 + rg * 8 + lrow) * C_DIM + kc0 + lcs * 8, &AH[rg * 512]);
            } else if (qidx < 32) {
                const int rg = qidx - 16;
                GLDS(xl + (size_t)(m0 + rg * 8 + lrow) * C_DIM + kc0 + lcs * 8, &AL[rg * 512]);
            } else if (qidx < 40) {
                const int rg = qidx - 32;
                GLDS(wth + (size_t)(bx * 64 + rg * 8 + lrow) * C_DIM + kc0 + lcs * 8, &BH[rg * 512]);
            } else {
                const int rg = qidx - 40;
                GLDS(wtl + (size_t)(bx * 64 + rg * 8 + lrow) * C_DIM + kc0 + lcs * 8, &BL[rg * 512]);
            }
        }
    };

    f32x4 acc[2][4];
    #pragma unroll
    for (int mt = 0; mt < 2; ++mt)
        #pragma unroll
        for (int ct = 0; ct < 4; ++ct) acc[mt][ct] = (f32x4){0.f, 0.f, 0.f, 0.f};

    const int swz = fm & 7;
    dma_chunk(0);
    #pragma unroll 1
    for (int c = 0; c < C_DIM / 64; ++c) {
        __syncthreads();
        half8 ah[2][2], al[2][2], bh[4][2], bl[4][2];
        #pragma unroll
        for (int mt = 0; mt < 2; ++mt) {
            const int rb = (wv * 32 + mt * 16 + fm) * 64;
            #pragma unroll
            for (int kc = 0; kc < 2; ++kc) {
                const int cb = ((kc * 4 + fg) ^ swz) * 8;
                ah[mt][kc] = *(const half8*)&AH[rb + cb];
                al[mt][kc] = *(const half8*)&AL[rb + cb];
            }
        }
        #pragma unroll
        for (int ct = 0; ct < 4; ++ct) {
            const int rb = (ct * 16 + fm) * 64;
            #pragma unroll
            for (int kc = 0; kc < 2; ++kc) {
                const int cb = ((kc * 4 + fg) ^ swz) * 8;
                bh[ct][kc] = *(const half8*)&BH[rb + cb];
                bl[ct][kc] = *(const half8*)&BL[rb + cb];
            }
        }
        __syncthreads();
        if (c + 1 < C_DIM / 64) dma_chunk(c + 1);
        #pragma unroll
        for (int mt = 0; mt < 2; ++mt)
            #pragma unroll
            for (int ct = 0; ct < 4; ++ct)
                #pragma unroll
                for (int kc = 0; kc < 2; ++kc) {
                    acc[mt][ct] = __builtin_amdgcn_mfma_f32_16x16x32_f16(ah[mt][kc], bh[ct][kc], acc[mt][ct], 0, 0, 0);
                    acc[mt][ct] = __builtin_amdgcn_mfma_f32_16x16x32_f16(ah[mt][kc], bl[ct][kc], acc[mt][ct], 0, 0, 0);
                    acc[mt][ct] = __builtin_amdgcn_mfma_f32_16x16x32_f16(al[mt][kc], bh[ct][kc], acc[mt][ct], 0, 0, 0);
                }
    }

    const int sec = bx / 12, h = bx % 12;
    const size_t hb = (size_t)h * HT;
    float bb[4];
    #pragma unroll
    for (int ct = 0; ct < 4; ++ct) bb[ct] = bias[bx * 64 + ct * 16 + fm];

    if (sec < 2) {
        _Float16* dh = (sec == 0) ? qhi : khi;
        _Float16* dl = (sec == 0) ? qlo : klo;
        #pragma unroll
        for (int mt = 0; mt < 2; ++mt)
            #pragma unroll
            for (int r = 0; r < 4; ++r) {
                float o[4];
                float ss = 0.f;
                #pragma unroll
                for (int ct = 0; ct < 4; ++ct) {
                    o[ct] = acc[mt][ct][r] + bb[ct];
                    ss += o[ct] * o[ct];
                }
                #pragma unroll
                for (int mk = 1; mk < 16; mk <<= 1) ss += __shfl_xor(ss, mk, 16);
                const float invn = 1.0f / fmaxf(sqrtf(ss), 1e-12f);
                const int t = m0 + wv * 32 + mt * 16 + fg * 4 + r;
                const size_t rb = hb + (size_t)t * HD;
                #pragma unroll
                for (int ct = 0; ct < 4; ++ct) {
                    const float v = o[ct] * invn;
                    const _Float16 vh = (_Float16)v;
                    dh[rb + ct * 16 + fm] = vh;
                    dl[rb + ct * 16 + fm] = (_Float16)(v - (float)vh);
                }
            }
    } else {
        #pragma unroll
        for (int mt = 0; mt < 2; ++mt) {
            const int t0 = m0 + wv * 32 + mt * 16 + fg * 4;
            #pragma unroll
            for (int ct = 0; ct < 4; ++ct) {
                half4 pk;
                #pragma unroll
                for (int r = 0; r < 4; ++r) pk[r] = (_Float16)(acc[mt][ct][r] + bb[ct]);
                *(half4*)(vt + hb + (size_t)(ct * 16 + fm) * T_SEQ + t0) = pk;
            }
        }
    }
}

// ---------------------------------------------------------------------------
// KSP: per head, exclusive prefix over 64-key tiles of Kn = khi+klo.
// ksphi/ksplo [h][kt=64][d=64], split f16. 12 blocks x 1024 threads.
// ---------------------------------------------------------------------------
__global__ __launch_bounds__(1024) void ksp_kernel(
    const _Float16* __restrict__ khi, const _Float16* __restrict__ klo,
    _Float16* __restrict__ ksphi, _Float16* __restrict__ ksplo)
{
    __shared__ float TS[64][64];
    const int h = blockIdx.x;
    const int d = threadIdx.x & 63, seg = threadIdx.x >> 6;   // 16 segs x 4 kt
    const _Float16* bh = khi + (size_t)h * HT;
    const _Float16* bl = klo + (size_t)h * HT;
    #pragma unroll 1
    for (int j = 0; j < 4; ++j) {
        const int kt = seg * 4 + j;
        float s = 0.f;
        #pragma unroll 4
        for (int k = 0; k < 64; ++k) {
            const size_t key = (size_t)kt * 64 + k;
            s += (float)bh[key * HD + d] + (float)bl[key * HD + d];
        }
        TS[kt][d] = s;
    }
    __syncthreads();
    if (threadIdx.x < 64) {
        float cum = 0.f;
        #pragma unroll 1
        for (int kt = 0; kt < 64; ++kt) {
            const _Float16 hi = (_Float16)cum;
            const size_t o = ((size_t)h * 64 + kt) * 64 + d;
            ksphi[o] = hi;
            ksplo[o] = (_Float16)(cum - (float)hi);
            cum += TS[kt][d];
        }
    }
}

// ---------------------------------------------------------------------------
// Fused attention, decoupled scan. 256 thr / 4 waves; wave wv owns key-tiles
// kt = it*4+wv (all 64 q-rows). No LDS staging, no in-loop barriers.
//   base[q][kt] = q . KSP[kt]  (96 MFMAs at start, kept in basv regs)
//   S^T = K.Q^T via 3x split-f16 MFMA; frags gathered from global (L2)
//   intra-64-key prefix: in-lane 4-chain + 2x shfl_xor butterfly
//   att*2^-5 -> f16 -> wave-private LDS -> A-frag for PV MFMA
//   partial Y per wave; cross-wave reduce through LDS at end.
// ---------------------------------------------------------------------------
__global__ __launch_bounds__(256, 2) void attn_kernel(
    const _Float16* __restrict__ qhi, const _Float16* __restrict__ qlo,
    const _Float16* __restrict__ khi, const _Float16* __restrict__ klo,
    const _Float16* __restrict__ vt,
    const _Float16* __restrict__ ksphi, const _Float16* __restrict__ ksplo,
    _Float16* __restrict__ ylin)
{
    __shared__ __align__(16) _Float16 P2[4][64][72];   // per-wave [q][key]; reused as f32 YR
    const int tid = threadIdx.x;
    const int wv = tid >> 6, lane = tid & 63;
    const int fm = lane & 15, fg = lane >> 4;
    const int h = blockIdx.y, qt = blockIdx.x;
    const size_t hb = (size_t)h * HT;

    // Q B-frags for all 4 q-subtiles (identical across waves, register-resident)
    half8 qf[4][2][2];   // [sub][plane][kc]
    #pragma unroll
    for (int s = 0; s < 4; ++s)
        #pragma unroll
        for (int kc = 0; kc < 2; ++kc) {
            const size_t off = hb + (size_t)(qt * 64 + s * 16 + fm) * HD + kc * 32 + fg * 8;
            qf[s][0][kc] = *(const half8*)(qhi + off);
            qf[s][1][kc] = *(const half8*)(qlo + off);
        }

    // base = Q . KSP : lane(fm,fg) of basv[s][kr] holds
    //   base[q = s*16+fm][kt = kr*16 + fg*4 + wv]
    f32x4 basv[4];
    {
        const _Float16* sh = ksphi + (size_t)h * 4096;
        const _Float16* sl = ksplo + (size_t)h * 4096;
        #pragma unroll
        for (int kr = 0; kr < 4; ++kr) {
            half8 kh_[2], kl_[2];
            #pragma unroll
            for (int kc = 0; kc < 2; ++kc) {
                const size_t o = (size_t)(kr * 16 + fm) * 64 + kc * 32 + fg * 8;
                kh_[kc] = *(const half8*)(sh + o);
                kl_[kc] = *(const half8*)(sl + o);
            }
            #pragma unroll
            for (int s = 0; s < 4; ++s) {
                f32x4 b = (f32x4){0.f, 0.f, 0.f, 0.f};
                #pragma unroll
                for (int kc = 0; kc < 2; ++kc) {
                    b = __builtin_amdgcn_mfma_f32_16x16x32_f16(kh_[kc], qf[s][0][kc], b, 0, 0, 0);
                    b = __builtin_amdgcn_mfma_f32_16x16x32_f16(kh_[kc], qf[s][1][kc], b, 0, 0, 0);
                    b = __builtin_amdgcn_mfma_f32_16x16x32_f16(kl_[kc], qf[s][0][kc], b, 0, 0, 0);
                }
                basv[s][kr] = (wv == 0) ? b[0] : (wv == 1) ? b[1] : (wv == 2) ? b[2] : b[3];
            }
        }
    }

    f32x4 yacc[4][4];
    #pragma unroll
    for (int s = 0; s < 4; ++s)
        #pragma unroll
        for (int ct = 0; ct < 4; ++ct) yacc[s][ct] = (f32x4){0.f, 0.f, 0.f, 0.f};

    #pragma unroll 1
    for (int it = 0; it < 16; ++it) {
        const int i4 = it >> 2, itf = it & 3;
        const int key0 = (it * 4 + wv) * 64;
        const size_t kb = hb + (size_t)key0 * HD;

        // K fragments (this wave's private 64 keys)
        half8 ka[4][2], kl2[4][2];
        #pragma unroll
        for (int kr = 0; kr < 4; ++kr)
            #pragma unroll
            for (int kc = 0; kc < 2; ++kc) {
                const size_t o = kb + (size_t)(kr * 16 + fm) * HD + kc * 32 + fg * 8;
                ka[kr][kc]  = *(const half8*)(khi + o);
                kl2[kr][kc] = *(const half8*)(klo + o);
            }

        // S^T = K.Q^T for all 4 q-subtiles
        f32x4 sacc[4][4];   // [sub][kr]
        #pragma unroll
        for (int s = 0; s < 4; ++s)
            #pragma unroll
            for (int kr = 0; kr < 4; ++kr) sacc[s][kr] = (f32x4){0.f, 0.f, 0.f, 0.f};
        #pragma unroll
        for (int kr = 0; kr < 4; ++kr)
            #pragma unroll
            for (int s = 0; s < 4; ++s)
                #pragma unroll
                for (int kc = 0; kc < 2; ++kc) {
                    sacc[s][kr] = __builtin_amdgcn_mfma_f32_16x16x32_f16(ka[kr][kc],  qf[s][0][kc], sacc[s][kr], 0, 0, 0);
                    sacc[s][kr] = __builtin_amdgcn_mfma_f32_16x16x32_f16(ka[kr][kc],  qf[s][1][kc], sacc[s][kr], 0, 0, 0);
                    sacc[s][kr] = __builtin_amdgcn_mfma_f32_16x16x32_f16(kl2[kr][kc], qf[s][0][kc], sacc[s][kr], 0, 0, 0);
                }

        // V fragments (issued here; latency covered by the scan below)
        half8 vf[4][2];
        #pragma unroll
        for (int ct = 0; ct < 4; ++ct)
            #pragma unroll
            for (int kc = 0; kc < 2; ++kc)
                vf[ct][kc] = *(const half8*)(vt + hb + (size_t)(ct * 16 + fm) * T_SEQ
                                             + key0 + kc * 32 + fg * 8);

        // scan + att -> P2 (wave-private)
        #pragma unroll
        for (int s = 0; s < 4; ++s) {
            const f32x4 bq = basv[s];
            const float bsel = (i4 == 0) ? bq[0] : (i4 == 1) ? bq[1] : (i4 == 2) ? bq[2] : bq[3];
            float loc = __shfl(bsel, itf * 16 + fm, 64);
            #pragma unroll
            for (int kr = 0; kr < 4; ++kr) {
                const float s0 = sacc[s][kr][0], s1 = sacc[s][kr][1];
                const float s2 = sacc[s][kr][2], s3 = sacc[s][kr][3];
                const float p1 = s0 + s1, p2 = p1 + s2, p3 = p2 + s3;
                const float u1 = __shfl_xor(p3, 16, 64);
                const float pair = p3 + u1;
                const float u2 = __shfl_xor(pair, 32, 64);
                const float tot16 = pair + u2;
                const float pref = ((fg & 1) ? u1 : 0.0f) + ((fg & 2) ? u2 : 0.0f);
                const float base = loc + pref;
                loc += tot16;
                const float a0 = s0 * __builtin_amdgcn_rcpf(fmaxf(base + s0, 1e-6f));
                const float a1 = s1 * __builtin_amdgcn_rcpf(fmaxf(base + p1, 1e-6f));
                const float a2 = s2 * __builtin_amdgcn_rcpf(fmaxf(base + p2, 1e-6f));
                const float a3 = s3 * __builtin_amdgcn_rcpf(fmaxf(base + p3, 1e-6f));
                half4 pk = {(_Float16)(a0 * 0.03125f), (_Float16)(a1 * 0.03125f),
                            (_Float16)(a2 * 0.03125f), (_Float16)(a3 * 0.03125f)};
                *(half4*)&P2[wv][s * 16 + fm][kr * 16 + fg * 4] = pk;
            }
        }

        // Y += att @ V (P2 round-trip wave-private: no barrier)
        #pragma unroll
        for (int s = 0; s < 4; ++s)
            #pragma unroll
            for (int kc = 0; kc < 2; ++kc) {
                const half8 af = *(const half8*)&P2[wv][s * 16 + fm][kc * 32 + fg * 8];
                #pragma unroll
                for (int ct = 0; ct < 4; ++ct)
                    yacc[s][ct] = __builtin_amdgcn_mfma_f32_16x16x32_f16(af, vf[ct][kc], yacc[s][ct], 0, 0, 0);
            }
    }

    // cross-wave Y reduction through LDS (reuse P2 as f32, row stride 66)
    __syncthreads();
    float* YR = (float*)&P2[0][0][0];
    #pragma unroll 1
    for (int w = 0; w < 4; ++w) {
        if (wv == w) {
            #pragma unroll
            for (int s = 0; s < 4; ++s)
                #pragma unroll
                for (int ct = 0; ct < 4; ++ct)
                    #pragma unroll
                    for (int r = 0; r < 4; ++r) {
                        const int qq = s * 16 + fg * 4 + r, dv = ct * 16 + fm;
                        if (w == 0) YR[qq * 66 + dv]  = yacc[s][ct][r];
                        else        YR[qq * 66 + dv] += yacc[s][ct][r];
                    }
        }
        __syncthreads();
    }
    // write ylin f16 = y * 2^-12 (acc holds y*2^-5 -> scale 2^-7)
    const int tq = tid >> 2, c0 = (tid & 3) * 16;
    const float* yr = &YR[tq * 66 + c0];
    half8 o0, o1;
    #pragma unroll
    for (int j = 0; j < 8; ++j) {
        o0[j] = (_Float16)(yr[j]     * 0.0078125f);
        o1[j] = (_Float16)(yr[8 + j] * 0.0078125f);
    }
    _Float16* dst = ylin + (size_t)(qt * 64 + tq) * C_DIM + h * HD + c0;
    *(half8*)dst       = o0;
    *(half8*)(dst + 8) = o1;
}

// ---------------------------------------------------------------------------
// Proj GEMM via f16 MFMA: ylin(f16, *2^-12)[4096,768] @ Wp[768,768] -> out fp32
// ---------------------------------------------------------------------------
__global__ __launch_bounds__(256) void gemm_proj_kernel(
    const _Float16* __restrict__ A, const float* __restrict__ W,
    const float* __restrict__ bias, float* __restrict__ out)
{
    __shared__ _Float16 As[64][72];
    __shared__ _Float16 Bt[64][72];
    typedef _Float16 half2v __attribute__((ext_vector_type(2)));
    const int tid = threadIdx.x;
    const int w = tid >> 6, lane = tid & 63;
    const int m = lane & 15, g = lane >> 4;
    const int row0 = blockIdx.x << 6, col0 = blockIdx.y << 6;
    const int ar = tid >> 3, ac8 = (tid & 7) << 3;
    const int bn0 = (tid & 15) << 2, bpv = tid >> 4;
    f32x4 acc[4];
    #pragma unroll
    for (int ct = 0; ct < 4; ++ct) acc[ct] = (f32x4){0.f, 0.f, 0.f, 0.f};

    for (int kt = 0; kt < C_DIM; kt += 64) {
        half8 av0 = *(const half8*)(A + (size_t)(row0 + ar)      * C_DIM + kt + ac8);
        half8 av1 = *(const half8*)(A + (size_t)(row0 + ar + 32) * C_DIM + kt + ac8);
        float4 w0[2], w1[2];
        #pragma unroll
        for (int i = 0; i < 2; ++i) {
            const int k = kt + 2 * (bpv + 16 * i);
            w0[i] = *(const float4*)(W + (size_t)k       * C_DIM + col0 + bn0);
            w1[i] = *(const float4*)(W + (size_t)(k + 1) * C_DIM + col0 + bn0);
        }
        __syncthreads();
        *(half8*)&As[ar][ac8]      = av0;
        *(half8*)&As[ar + 32][ac8] = av1;
        #pragma unroll
        for (int i = 0; i < 2; ++i) {
            const int p = bpv + 16 * i;
            const float a_[4] = {w0[i].x, w0[i].y, w0[i].z, w0[i].w};
            const float b_[4] = {w1[i].x, w1[i].y, w1[i].z, w1[i].w};
            #pragma unroll
            for (int u = 0; u < 4; ++u) {
                half2v pk = {(_Float16)a_[u], (_Float16)b_[u]};
                *(half2v*)&Bt[bn0 + u][2 * p] = pk;
            }
        }
        __syncthreads();
        #pragma unroll
        for (int kc = 0; kc < 2; ++kc) {
            const half8 a = *(half8*)&As[w * 16 + m][kc * 32 + g * 8];
            #pragma unroll
            for (int ct = 0; ct < 4; ++ct) {
                const half8 b = *(half8*)&Bt[ct * 16 + m][kc * 32 + g * 8];
                acc[ct] = __builtin_amdgcn_mfma_f32_16x16x32_f16(a, b, acc[ct], 0, 0, 0);
            }
        }
    }
    #pragma unroll
    for (int ct = 0; ct < 4; ++ct)
        #pragma unroll
        for (int r = 0; r < 4; ++r) {
            const int t = row0 + w * 16 + g * 4 + r;
            const int n = col0 + ct * 16 + m;
            out[(size_t)t * C_DIM + n] = acc[ct][r] * 4096.0f + bias[n];
        }
}

extern "C" void kernel_launch(void* const* d_in, const int* in_sizes, int n_in,
                              void* d_out, int out_size, void* d_ws, size_t ws_size,
                              hipStream_t stream)
{
    const float* x      = (const float*)d_in[0];
    const float* w_attn = (const float*)d_in[1];
    const float* b_attn = (const float*)d_in[2];
    const float* w_proj = (const float*)d_in[3];
    const float* b_proj = (const float*)d_in[4];
    float* out = (float*)d_out;

    const size_t perQK = (size_t)H_NUM * HT;      // 3,145,728
    const size_t perX  = (size_t)T_SEQ * C_DIM;   // 3,145,728
    const size_t perW  = (size_t)N_QKV * C_DIM;   // 1,769,472
    _Float16* base = (_Float16*)d_ws;
    _Float16* xhi  = base;
    _Float16* xlo  = xhi + perX;
    _Float16* wthi = xlo + perX;
    _Float16* wtlo = wthi + perW;
    _Float16* qhi  = wtlo + perW;
    _Float16* qlo  = qhi + perQK;
    _Float16* khi  = qlo + perQK;
    _Float16* klo  = khi + perQK;
    _Float16* vtp  = klo + perQK;
    _Float16* ylin = xhi;                          // xhi dead after qkv
    _Float16* ksph = xlo;                          // xlo dead after qkv
    _Float16* kspl = xlo + (size_t)H_NUM * 64 * 64;

    split_x_kernel<<<(perX / 4 + 255) / 256, 256, 0, stream>>>(x, xhi, xlo, perX / 4);
    split_wt_kernel<<<dim3(N_QKV / 64, C_DIM / 64), 256, 0, stream>>>(w_attn, wthi, wtlo);
    gemm_qkv_kernel<<<dim3(N_QKV / 64, T_SEQ / 128), 256, 0, stream>>>(
        xhi, xlo, wthi, wtlo, b_attn, qhi, qlo, khi, klo, vtp);
    ksp_kernel<<<H_NUM, 1024, 0, stream>>>(khi, klo, ksph, kspl);
    attn_kernel<<<dim3(T_SEQ / 64, H_NUM), 256, 0, stream>>>(
        qhi, qlo, khi, klo, vtp, ksph, kspl, ylin);
    gemm_proj_kernel<<<dim3(T_SEQ / 64, C_DIM / 64), 256, 0, stream>>>(
        ylin, w_proj, b_proj, out);
}

// Round 6
// 393.036 us; speedup vs baseline: 1.1167x; 1.1167x over previous
//
#include <hip/hip_runtime.h>

#define T_SEQ 4096
#define H_NUM 12
#define HD    64
#define C_DIM 768
#define N_QKV 2304
#define HT    (T_SEQ * HD)   // per-head elements = 262144

typedef float    f32x4 __attribute__((ext_vector_type(4)));
typedef _Float16 half8 __attribute__((ext_vector_type(8)));
typedef _Float16 half4 __attribute__((ext_vector_type(4)));

// async global->LDS, 16B/lane, dest = wave-uniform base + lane*16
#define GLDS(gp, lp) __builtin_amdgcn_global_load_lds( \
    (const __attribute__((address_space(1))) void*)(gp), \
    (__attribute__((address_space(3))) void*)(lp), 16, 0, 0)

// s_waitcnt immediates (gfx9 encoding): vmcnt[3:0]|[15:14], expcnt[6:4], lgkmcnt[11:8]
#define WAIT_VM0   0x0F70   // vmcnt(0), others max
#define WAIT_LGKM0 0xC07F   // lgkmcnt(0), others max

#define SEL8(a, i) ((i) < 4 ? ((i) < 2 ? ((i) == 0 ? (a)[0] : (a)[1])   \
                                       : ((i) == 2 ? (a)[2] : (a)[3]))  \
                            : ((i) < 6 ? ((i) == 4 ? (a)[4] : (a)[5])   \
                                       : ((i) == 6 ? (a)[6] : (a)[7])))

// ---------------------------------------------------------------------------
// split x (fp32) -> xhi + xlo (f16 planes)
// ---------------------------------------------------------------------------
__global__ __launch_bounds__(256) void split_x_kernel(
    const float* __restrict__ x, _Float16* __restrict__ xh,
    _Float16* __restrict__ xl, int n4)
{
    const int i = blockIdx.x * 256 + threadIdx.x;
    if (i >= n4) return;
    const float4 v = ((const float4*)x)[i];
    const float vv[4] = {v.x, v.y, v.z, v.w};
    half4 h, l;
    #pragma unroll
    for (int j = 0; j < 4; ++j) {
        const _Float16 hh = (_Float16)vv[j];
        h[j] = hh;
        l[j] = (_Float16)(vv[j] - (float)hh);
    }
    ((half4*)xh)[i] = h;
    ((half4*)xl)[i] = l;
}

// ---------------------------------------------------------------------------
// transpose+split w_attn [768][2304] -> wthi/wtlo [2304][768] (f16)
// ---------------------------------------------------------------------------
__global__ __launch_bounds__(256) void split_wt_kernel(
    const float* __restrict__ W, _Float16* __restrict__ wth,
    _Float16* __restrict__ wtl)
{
    __shared__ float Ws[64][65];
    const int tid = threadIdx.x;
    const int n0 = blockIdx.x * 64, k0 = blockIdx.y * 64;
    const int lr = tid >> 4, lc = (tid & 15) << 2;
    #pragma unroll
    for (int i = 0; i < 4; ++i) {
        const float4 v = *(const float4*)(W + (size_t)(k0 + lr + i * 16) * N_QKV + n0 + lc);
        Ws[lr + i * 16][lc + 0] = v.x; Ws[lr + i * 16][lc + 1] = v.y;
        Ws[lr + i * 16][lc + 2] = v.z; Ws[lr + i * 16][lc + 3] = v.w;
    }
    __syncthreads();
    const int n = tid >> 2, ks = (tid & 3) << 4;
    half8 h0, h1, l0, l1;
    #pragma unroll
    for (int j = 0; j < 8; ++j) {
        const float v = Ws[ks + j][n];
        const _Float16 hh = (_Float16)v;
        h0[j] = hh; l0[j] = (_Float16)(v - (float)hh);
    }
    #pragma unroll
    for (int j = 0; j < 8; ++j) {
        const float v = Ws[ks + 8 + j][n];
        const _Float16 hh = (_Float16)v;
        h1[j] = hh; l1[j] = (_Float16)(v - (float)hh);
    }
    const size_t dst = (size_t)(n0 + n) * C_DIM + k0 + ks;
    *(half8*)(wth + dst) = h0; *(half8*)(wth + dst + 8) = h1;
    *(half8*)(wtl + dst) = l0; *(half8*)(wtl + dst + 8) = l1;
}

// ---------------------------------------------------------------------------
// QKV GEMM via split-f16 MFMA (AhBh + AhBl + AlBh), 128m x 64n tile, BK=64.
// Epilogue: bias + l2norm + hi/lo split (q,k) or bias + V transpose (v).
// ---------------------------------------------------------------------------
__global__ __launch_bounds__(256) void gemm_qkv_kernel(
    const _Float16* __restrict__ xh, const _Float16* __restrict__ xl,
    const _Float16* __restrict__ wth, const _Float16* __restrict__ wtl,
    const float* __restrict__ bias,
    _Float16* __restrict__ qhi, _Float16* __restrict__ qlo,
    _Float16* __restrict__ khi, _Float16* __restrict__ klo,
    _Float16* __restrict__ vt)
{
    __shared__ __align__(16) _Float16 AH[128 * 64];
    __shared__ __align__(16) _Float16 AL[128 * 64];
    __shared__ __align__(16) _Float16 BH[64 * 64];
    __shared__ __align__(16) _Float16 BL[64 * 64];
    const int tid = threadIdx.x;
    const int wv = tid >> 6, lane = tid & 63;
    const int fm = lane & 15, fg = lane >> 4;
    const int lrow = lane >> 3;
    const int lcs  = (lane & 7) ^ (lrow & 7);
    const int bx = blockIdx.x;
    const int m0 = blockIdx.y * 128;

    auto dma_chunk = [&](int c) {
        const int kc0 = c * 64;
        #pragma unroll
        for (int i = 0; i < 12; ++i) {
            const int qidx = wv * 12 + i;
            if (qidx < 16) {
                const int rg = qidx;
                GLDS(xh + (size_t)(m0 + rg * 8 + lrow) * C_DIM + kc0 + lcs * 8, &AH[rg * 512]);
            } else if (qidx < 32) {
                const int rg = qidx - 16;
                GLDS(xl + (size_t)(m0 + rg * 8 + lrow) * C_DIM + kc0 + lcs * 8, &AL[rg * 512]);
            } else if (qidx < 40) {
                const int rg = qidx - 32;
                GLDS(wth + (size_t)(bx * 64 + rg * 8 + lrow) * C_DIM + kc0 + lcs * 8, &BH[rg * 512]);
            } else {
                const int rg = qidx - 40;
                GLDS(wtl + (size_t)(bx * 64 + rg * 8 + lrow) * C_DIM + kc0 + lcs * 8, &BL[rg * 512]);
            }
        }
    };

    f32x4 acc[2][4];
    #pragma unroll
    for (int mt = 0; mt < 2; ++mt)
        #pragma unroll
        for (int ct = 0; ct < 4; ++ct) acc[mt][ct] = (f32x4){0.f, 0.f, 0.f, 0.f};

    const int swz = fm & 7;
    dma_chunk(0);
    #pragma unroll 1
    for (int c = 0; c < C_DIM / 64; ++c) {
        __syncthreads();
        half8 ah[2][2], al[2][2], bh[4][2], bl[4][2];
        #pragma unroll
        for (int mt = 0; mt < 2; ++mt) {
            const int rb = (wv * 32 + mt * 16 + fm) * 64;
            #pragma unroll
            for (int kc = 0; kc < 2; ++kc) {
                const int cb = ((kc * 4 + fg) ^ swz) * 8;
                ah[mt][kc] = *(const half8*)&AH[rb + cb];
                al[mt][kc] = *(const half8*)&AL[rb + cb];
            }
        }
        #pragma unroll
        for (int ct = 0; ct < 4; ++ct) {
            const int rb = (ct * 16 + fm) * 64;
            #pragma unroll
            for (int kc = 0; kc < 2; ++kc) {
                const int cb = ((kc * 4 + fg) ^ swz) * 8;
                bh[ct][kc] = *(const half8*)&BH[rb + cb];
                bl[ct][kc] = *(const half8*)&BL[rb + cb];
            }
        }
        __syncthreads();
        if (c + 1 < C_DIM / 64) dma_chunk(c + 1);
        #pragma unroll
        for (int mt = 0; mt < 2; ++mt)
            #pragma unroll
            for (int ct = 0; ct < 4; ++ct)
                #pragma unroll
                for (int kc = 0; kc < 2; ++kc) {
                    acc[mt][ct] = __builtin_amdgcn_mfma_f32_16x16x32_f16(ah[mt][kc], bh[ct][kc], acc[mt][ct], 0, 0, 0);
                    acc[mt][ct] = __builtin_amdgcn_mfma_f32_16x16x32_f16(ah[mt][kc], bl[ct][kc], acc[mt][ct], 0, 0, 0);
                    acc[mt][ct] = __builtin_amdgcn_mfma_f32_16x16x32_f16(al[mt][kc], bh[ct][kc], acc[mt][ct], 0, 0, 0);
                }
    }

    const int sec = bx / 12, h = bx % 12;
    const size_t hb = (size_t)h * HT;
    float bb[4];
    #pragma unroll
    for (int ct = 0; ct < 4; ++ct) bb[ct] = bias[bx * 64 + ct * 16 + fm];

    if (sec < 2) {
        _Float16* dh = (sec == 0) ? qhi : khi;
        _Float16* dl = (sec == 0) ? qlo : klo;
        #pragma unroll
        for (int mt = 0; mt < 2; ++mt)
            #pragma unroll
            for (int r = 0; r < 4; ++r) {
                float o[4];
                float ss = 0.f;
                #pragma unroll
                for (int ct = 0; ct < 4; ++ct) {
                    o[ct] = acc[mt][ct][r] + bb[ct];
                    ss += o[ct] * o[ct];
                }
                #pragma unroll
                for (int mk = 1; mk < 16; mk <<= 1) ss += __shfl_xor(ss, mk, 16);
                const float invn = 1.0f / fmaxf(sqrtf(ss), 1e-12f);
                const int t = m0 + wv * 32 + mt * 16 + fg * 4 + r;
                const size_t rb = hb + (size_t)t * HD;
                #pragma unroll
                for (int ct = 0; ct < 4; ++ct) {
                    const float v = o[ct] * invn;
                    const _Float16 vh = (_Float16)v;
                    dh[rb + ct * 16 + fm] = vh;
                    dl[rb + ct * 16 + fm] = (_Float16)(v - (float)vh);
                }
            }
    } else {
        #pragma unroll
        for (int mt = 0; mt < 2; ++mt) {
            const int t0 = m0 + wv * 32 + mt * 16 + fg * 4;
            #pragma unroll
            for (int ct = 0; ct < 4; ++ct) {
                half4 pk;
                #pragma unroll
                for (int r = 0; r < 4; ++r) pk[r] = (_Float16)(acc[mt][ct][r] + bb[ct]);
                *(half4*)(vt + hb + (size_t)(ct * 16 + fm) * T_SEQ + t0) = pk;
            }
        }
    }
}

// ---------------------------------------------------------------------------
// KSP: per head, exclusive prefix over 32-key tiles of Kn = khi+klo.
// ksphi/ksplo [h][t32=128][d=64], split f16. 12 blocks x 1024 threads.
// ---------------------------------------------------------------------------
__global__ __launch_bounds__(1024) void ksp_kernel(
    const _Float16* __restrict__ khi, const _Float16* __restrict__ klo,
    _Float16* __restrict__ ksphi, _Float16* __restrict__ ksplo)
{
    __shared__ float TS[128][64];
    const int h = blockIdx.x;
    const int d = threadIdx.x & 63, seg = threadIdx.x >> 6;   // 16 segs x 8 tiles
    const _Float16* bh = khi + (size_t)h * HT;
    const _Float16* bl = klo + (size_t)h * HT;
    #pragma unroll 1
    for (int j = 0; j < 8; ++j) {
        const int kt = seg * 8 + j;
        float s = 0.f;
        #pragma unroll 4
        for (int k = 0; k < 32; ++k) {
            const size_t key = (size_t)kt * 32 + k;
            s += (float)bh[key * HD + d] + (float)bl[key * HD + d];
        }
        TS[kt][d] = s;
    }
    __syncthreads();
    if (threadIdx.x < 64) {
        float cum = 0.f;
        #pragma unroll 1
        for (int kt = 0; kt < 128; ++kt) {
            const _Float16 hi = (_Float16)cum;
            const size_t o = ((size_t)h * 128 + kt) * 64 + d;
            ksphi[o] = hi;
            ksplo[o] = (_Float16)(cum - (float)hi);
            cum += TS[kt][d];
        }
    }
}

// ---------------------------------------------------------------------------
// Fused attention: key-split waves + wave-private DMA staging, NO in-loop
// barriers. Wave wv owns 32-key tiles t32 = 4*it+wv (it=0..31), all 64 q.
//   base[q][t32] = q.KSP[t32]  (192 MFMAs at start -> basv regs, reg idx = wv)
//   K hi/lo staged per-wave via swizzled global_load_lds; drain = s_waitcnt
//   vmcnt(0) (manual, 0x0F70). V frags direct global (issued at iter top).
//   S^T = K.Q^T 3x split-f16 MFMA; scan in-lane chain + shfl_xor butterfly;
//   att*2^-5 -> f16 -> wave-private P2 -> A-frag for PV (K=32) MFMA.
//   Partial Y per wave; cross-wave LDS reduce at end.
// ---------------------------------------------------------------------------
__global__ __launch_bounds__(256, 2) void attn_kernel(
    const _Float16* __restrict__ qhi, const _Float16* __restrict__ qlo,
    const _Float16* __restrict__ khi, const _Float16* __restrict__ klo,
    const _Float16* __restrict__ vt,
    const _Float16* __restrict__ ksphi, const _Float16* __restrict__ ksplo,
    _Float16* __restrict__ ylin)
{
    // [0, 32768): per-wave K staging (wv*8192B: hi 4KB + lo 4KB), swizzled
    // [32768, 53248): per-wave P2 (64 q x 40 halfs)
    // epilogue: [0, 16896) reused as f32 YR (stride 66)
    __shared__ __align__(16) unsigned char SMEM[53248];
    const int tid = threadIdx.x;
    const int wv = tid >> 6, lane = tid & 63;
    const int fm = lane & 15, fg = lane >> 4;
    const int h = blockIdx.y, qt = blockIdx.x;
    const size_t hb = (size_t)h * HT;

    _Float16* KSw = (_Float16*)SMEM + (size_t)wv * 4096;
    _Float16* P2w = (_Float16*)(SMEM + 32768) + (size_t)wv * (64 * 40);

    // Q B-frags for the block's 64 q rows (identical in all waves)
    half8 qf[4][2][2];   // [sub][plane][kc]
    #pragma unroll
    for (int s = 0; s < 4; ++s)
        #pragma unroll
        for (int kc = 0; kc < 2; ++kc) {
            const size_t off = hb + (size_t)(qt * 64 + s * 16 + fm) * HD + kc * 32 + fg * 8;
            qf[s][0][kc] = *(const half8*)(qhi + off);
            qf[s][1][kc] = *(const half8*)(qlo + off);
        }

    auto dma_k = [&](int key0) {
        const int r8 = lane >> 3;
        const int sc = (lane & 7) ^ (r8 & 7);
        const size_t srow = hb + (size_t)key0 * HD + sc * 8;
        _Float16* dl = KSw + 2048;
        #pragma unroll
        for (int i = 0; i < 4; ++i) {
            GLDS(khi + srow + (size_t)(i * 8 + r8) * HD, KSw + i * 512);
            GLDS(klo + srow + (size_t)(i * 8 + r8) * HD, dl  + i * 512);
        }
    };
    dma_k(wv * 32);   // tile for it=0

    // base = Q . KSP : basv[s][kr] = base[q = s*16+fm][t32 = kr*16 + fg*4 + wv]
    float basv[4][8];
    {
        const _Float16* sh = ksphi + (size_t)h * 8192;
        const _Float16* sl = ksplo + (size_t)h * 8192;
        #pragma unroll
        for (int kr = 0; kr < 8; ++kr) {
            half8 kh_[2], kl_[2];
            #pragma unroll
            for (int kc = 0; kc < 2; ++kc) {
                const size_t o = (size_t)(kr * 16 + fm) * 64 + kc * 32 + fg * 8;
                kh_[kc] = *(const half8*)(sh + o);
                kl_[kc] = *(const half8*)(sl + o);
            }
            #pragma unroll
            for (int s = 0; s < 4; ++s) {
                f32x4 b = (f32x4){0.f, 0.f, 0.f, 0.f};
                #pragma unroll
                for (int kc = 0; kc < 2; ++kc) {
                    b = __builtin_amdgcn_mfma_f32_16x16x32_f16(kh_[kc], qf[s][0][kc], b, 0, 0, 0);
                    b = __builtin_amdgcn_mfma_f32_16x16x32_f16(kh_[kc], qf[s][1][kc], b, 0, 0, 0);
                    b = __builtin_amdgcn_mfma_f32_16x16x32_f16(kl_[kc], qf[s][0][kc], b, 0, 0, 0);
                }
                basv[s][kr] = (wv == 0) ? b[0] : (wv == 1) ? b[1] : (wv == 2) ? b[2] : b[3];
            }
        }
    }

    f32x4 yacc[4][4];
    #pragma unroll
    for (int s = 0; s < 4; ++s)
        #pragma unroll
        for (int ct = 0; ct < 4; ++ct) yacc[s][ct] = (f32x4){0.f, 0.f, 0.f, 0.f};

    const int swz = fm & 7;
    float bs[4] = {0.f, 0.f, 0.f, 0.f};

    #pragma unroll 1
    for (int it = 0; it < 32; ++it) {
        const int ii = it & 3;
        if (ii == 0) {
            const int io = it >> 2;
            bs[0] = SEL8(basv[0], io);
            bs[1] = SEL8(basv[1], io);
            bs[2] = SEL8(basv[2], io);
            bs[3] = SEL8(basv[3], io);
        }
        const int key0 = (it * 4 + wv) * 32;

        __builtin_amdgcn_s_waitcnt(WAIT_VM0);   // staged K(it) landed

        // V frags direct from global (used at PV; ~whole-iter latency cover)
        half8 vfr[4];
        #pragma unroll
        for (int ct = 0; ct < 4; ++ct)
            vfr[ct] = *(const half8*)(vt + hb + (size_t)(ct * 16 + fm) * T_SEQ
                                      + key0 + fg * 8);

        // K frags from wave-private staging
        half8 ka[2][2], klr[2][2];
        #pragma unroll
        for (int kr = 0; kr < 2; ++kr)
            #pragma unroll
            for (int kc = 0; kc < 2; ++kc) {
                const int off = (kr * 16 + fm) * 64 + (((kc * 4 + fg) ^ swz) * 8);
                ka[kr][kc]  = *(const half8*)(KSw + off);
                klr[kr][kc] = *(const half8*)(KSw + 2048 + off);
            }
        __builtin_amdgcn_s_waitcnt(WAIT_LGKM0);  // staged reads retired
        if (it + 1 < 32) dma_k(((it + 1) * 4 + wv) * 32);   // overlaps compute

        // per q-subtile: S^T MFMA + scan + P2 write
        #pragma unroll
        for (int s = 0; s < 4; ++s) {
            f32x4 sacc[2];
            sacc[0] = (f32x4){0.f, 0.f, 0.f, 0.f};
            sacc[1] = (f32x4){0.f, 0.f, 0.f, 0.f};
            #pragma unroll
            for (int kr = 0; kr < 2; ++kr)
                #pragma unroll
                for (int kc = 0; kc < 2; ++kc) {
                    sacc[kr] = __builtin_amdgcn_mfma_f32_16x16x32_f16(ka[kr][kc],  qf[s][0][kc], sacc[kr], 0, 0, 0);
                    sacc[kr] = __builtin_amdgcn_mfma_f32_16x16x32_f16(ka[kr][kc],  qf[s][1][kc], sacc[kr], 0, 0, 0);
                    sacc[kr] = __builtin_amdgcn_mfma_f32_16x16x32_f16(klr[kr][kc], qf[s][0][kc], sacc[kr], 0, 0, 0);
                }
            float loc = __shfl(bs[s], ii * 16 + fm, 64);
            #pragma unroll
            for (int kr = 0; kr < 2; ++kr) {
                const float s0 = sacc[kr][0], s1 = sacc[kr][1];
                const float s2 = sacc[kr][2], s3 = sacc[kr][3];
                const float p1 = s0 + s1, p2 = p1 + s2, p3 = p2 + s3;
                const float u1 = __shfl_xor(p3, 16, 64);
                const float pair = p3 + u1;
                const float u2 = __shfl_xor(pair, 32, 64);
                const float tot16 = pair + u2;
                const float pref = ((fg & 1) ? u1 : 0.0f) + ((fg & 2) ? u2 : 0.0f);
                const float base = loc + pref;
                loc += tot16;
                const float a0 = s0 * __builtin_amdgcn_rcpf(fmaxf(base + s0, 1e-6f));
                const float a1 = s1 * __builtin_amdgcn_rcpf(fmaxf(base + p1, 1e-6f));
                const float a2 = s2 * __builtin_amdgcn_rcpf(fmaxf(base + p2, 1e-6f));
                const float a3 = s3 * __builtin_amdgcn_rcpf(fmaxf(base + p3, 1e-6f));
                half4 pk = {(_Float16)(a0 * 0.03125f), (_Float16)(a1 * 0.03125f),
                            (_Float16)(a2 * 0.03125f), (_Float16)(a3 * 0.03125f)};
                *(half4*)(P2w + (s * 16 + fm) * 40 + kr * 16 + fg * 4) = pk;
            }
        }

        // Y += att @ V  (wave-private P2 round-trip; K=32 covers the tile)
        #pragma unroll
        for (int s = 0; s < 4; ++s) {
            const half8 ap = *(const half8*)(P2w + (s * 16 + fm) * 40 + fg * 8);
            #pragma unroll
            for (int ct = 0; ct < 4; ++ct)
                yacc[s][ct] = __builtin_amdgcn_mfma_f32_16x16x32_f16(ap, vfr[ct], yacc[s][ct], 0, 0, 0);
        }
    }

    // cross-wave Y reduction through LDS (f32, stride 66)
    __syncthreads();
    float* YR = (float*)SMEM;
    #pragma unroll 1
    for (int w = 0; w < 4; ++w) {
        if (wv == w) {
            #pragma unroll
            for (int s = 0; s < 4; ++s)
                #pragma unroll
                for (int ct = 0; ct < 4; ++ct)
                    #pragma unroll
                    for (int r = 0; r < 4; ++r) {
                        const int qq = s * 16 + fg * 4 + r, dv = ct * 16 + fm;
                        if (w == 0) YR[qq * 66 + dv]  = yacc[s][ct][r];
                        else        YR[qq * 66 + dv] += yacc[s][ct][r];
                    }
        }
        __syncthreads();
    }
    // write ylin f16 = y * 2^-12 (acc holds y*2^-5 -> scale 2^-7)
    const int tq = tid >> 2, c0 = (tid & 3) * 16;
    const float* yr = &YR[tq * 66 + c0];
    half8 o0, o1;
    #pragma unroll
    for (int j = 0; j < 8; ++j) {
        o0[j] = (_Float16)(yr[j]     * 0.0078125f);
        o1[j] = (_Float16)(yr[8 + j] * 0.0078125f);
    }
    _Float16* dst = ylin + (size_t)(qt * 64 + tq) * C_DIM + h * HD + c0;
    *(half8*)dst       = o0;
    *(half8*)(dst + 8) = o1;
}

// ---------------------------------------------------------------------------
// Proj GEMM via f16 MFMA: ylin(f16, *2^-12)[4096,768] @ Wp[768,768] -> out fp32
// ---------------------------------------------------------------------------
__global__ __launch_bounds__(256) void gemm_proj_kernel(
    const _Float16* __restrict__ A, const float* __restrict__ W,
    const float* __restrict__ bias, float* __restrict__ out)
{
    __shared__ _Float16 As[64][72];
    __shared__ _Float16 Bt[64][72];
    typedef _Float16 half2v __attribute__((ext_vector_type(2)));
    const int tid = threadIdx.x;
    const int w = tid >> 6, lane = tid & 63;
    const int m = lane & 15, g = lane >> 4;
    const int row0 = blockIdx.x << 6, col0 = blockIdx.y << 6;
    const int ar = tid >> 3, ac8 = (tid & 7) << 3;
    const int bn0 = (tid & 15) << 2, bpv = tid >> 4;
    f32x4 acc[4];
    #pragma unroll
    for (int ct = 0; ct < 4; ++ct) acc[ct] = (f32x4){0.f, 0.f, 0.f, 0.f};

    for (int kt = 0; kt < C_DIM; kt += 64) {
        half8 av0 = *(const half8*)(A + (size_t)(row0 + ar)      * C_DIM + kt + ac8);
        half8 av1 = *(const half8*)(A + (size_t)(row0 + ar + 32) * C_DIM + kt + ac8);
        float4 w0[2], w1[2];
        #pragma unroll
        for (int i = 0; i < 2; ++i) {
            const int k = kt + 2 * (bpv + 16 * i);
            w0[i] = *(const float4*)(W + (size_t)k       * C_DIM + col0 + bn0);
            w1[i] = *(const float4*)(W + (size_t)(k + 1) * C_DIM + col0 + bn0);
        }
        __syncthreads();
        *(half8*)&As[ar][ac8]      = av0;
        *(half8*)&As[ar + 32][ac8] = av1;
        #pragma unroll
        for (int i = 0; i < 2; ++i) {
            const int p = bpv + 16 * i;
            const float a_[4] = {w0[i].x, w0[i].y, w0[i].z, w0[i].w};
            const float b_[4] = {w1[i].x, w1[i].y, w1[i].z, w1[i].w};
            #pragma unroll
            for (int u = 0; u < 4; ++u) {
                half2v pk = {(_Float16)a_[u], (_Float16)b_[u]};
                *(half2v*)&Bt[bn0 + u][2 * p] = pk;
            }
        }
        __syncthreads();
        #pragma unroll
        for (int kc = 0; kc < 2; ++kc) {
            const half8 a = *(half8*)&As[w * 16 + m][kc * 32 + g * 8];
            #pragma unroll
            for (int ct = 0; ct < 4; ++ct) {
                const half8 b = *(half8*)&Bt[ct * 16 + m][kc * 32 + g * 8];
                acc[ct] = __builtin_amdgcn_mfma_f32_16x16x32_f16(a, b, acc[ct], 0, 0, 0);
            }
        }
    }
    #pragma unroll
    for (int ct = 0; ct < 4; ++ct)
        #pragma unroll
        for (int r = 0; r < 4; ++r) {
            const int t = row0 + w * 16 + g * 4 + r;
            const int n = col0 + ct * 16 + m;
            out[(size_t)t * C_DIM + n] = acc[ct][r] * 4096.0f + bias[n];
        }
}

extern "C" void kernel_launch(void* const* d_in, const int* in_sizes, int n_in,
                              void* d_out, int out_size, void* d_ws, size_t ws_size,
                              hipStream_t stream)
{
    const float* x      = (const float*)d_in[0];
    const float* w_attn = (const float*)d_in[1];
    const float* b_attn = (const float*)d_in[2];
    const float* w_proj = (const float*)d_in[3];
    const float* b_proj = (const float*)d_in[4];
    float* out = (float*)d_out;

    const size_t perQK = (size_t)H_NUM * HT;      // 3,145,728
    const size_t perX  = (size_t)T_SEQ * C_DIM;   // 3,145,728
    const size_t perW  = (size_t)N_QKV * C_DIM;   // 1,769,472
    _Float16* base = (_Float16*)d_ws;
    _Float16* xhi  = base;
    _Float16* xlo  = xhi + perX;
    _Float16* wthi = xlo + perX;
    _Float16* wtlo = wthi + perW;
    _Float16* qhi  = wtlo + perW;
    _Float16* qlo  = qhi + perQK;
    _Float16* khi  = qlo + perQK;
    _Float16* klo  = khi + perQK;
    _Float16* vtp  = klo + perQK;
    _Float16* ylin = xhi;                          // xhi dead after qkv
    _Float16* ksph = xlo;                          // xlo dead after qkv
    _Float16* kspl = xlo + (size_t)H_NUM * 128 * 64;

    split_x_kernel<<<(perX / 4 + 255) / 256, 256, 0, stream>>>(x, xhi, xlo, perX / 4);
    split_wt_kernel<<<dim3(N_QKV / 64, C_DIM / 64), 256, 0, stream>>>(w_attn, wthi, wtlo);
    gemm_qkv_kernel<<<dim3(N_QKV / 64, T_SEQ / 128), 256, 0, stream>>>(
        xhi, xlo, wthi, wtlo, b_attn, qhi, qlo, khi, klo, vtp);
    ksp_kernel<<<H_NUM, 1024, 0, stream>>>(khi, klo, ksph, kspl);
    attn_kernel<<<dim3(T_SEQ / 64, H_NUM), 256, 0, stream>>>(
        qhi, qlo, khi, klo, vtp, ksph, kspl, ylin);
    gemm_proj_kernel<<<dim3(T_SEQ / 64, C_DIM / 64), 256, 0, stream>>>(
        ylin, w_proj, b_proj, out);
}

// Round 7
// 376.036 us; speedup vs baseline: 1.1672x; 1.0452x over previous
//
#include <hip/hip_runtime.h>

#define T_SEQ 4096
#define H_NUM 12
#define HD    64
#define C_DIM 768
#define N_QKV 2304
#define HT    (T_SEQ * HD)   // per-head elements = 262144

typedef float    f32x4 __attribute__((ext_vector_type(4)));
typedef _Float16 half8 __attribute__((ext_vector_type(8)));
typedef _Float16 half4 __attribute__((ext_vector_type(4)));

// async global->LDS, 16B/lane, dest = wave-uniform base + lane*16
#define GLDS(gp, lp) __builtin_amdgcn_global_load_lds( \
    (const __attribute__((address_space(1))) void*)(gp), \
    (__attribute__((address_space(3))) void*)(lp), 16, 0, 0)

// s_waitcnt immediates (gfx9 encoding): vmcnt[3:0]|[15:14], expcnt[6:4], lgkmcnt[11:8]
#define WAIT_VM0   0x0F70   // vmcnt(0), others max
#define WAIT_LGKM0 0xC07F   // lgkmcnt(0), others max

// ---------------------------------------------------------------------------
// split x (fp32) -> xhi + xlo (f16 planes)
// ---------------------------------------------------------------------------
__global__ __launch_bounds__(256) void split_x_kernel(
    const float* __restrict__ x, _Float16* __restrict__ xh,
    _Float16* __restrict__ xl, int n4)
{
    const int i = blockIdx.x * 256 + threadIdx.x;
    if (i >= n4) return;
    const float4 v = ((const float4*)x)[i];
    const float vv[4] = {v.x, v.y, v.z, v.w};
    half4 h, l;
    #pragma unroll
    for (int j = 0; j < 4; ++j) {
        const _Float16 hh = (_Float16)vv[j];
        h[j] = hh;
        l[j] = (_Float16)(vv[j] - (float)hh);
    }
    ((half4*)xh)[i] = h;
    ((half4*)xl)[i] = l;
}

// ---------------------------------------------------------------------------
// transpose+split w_attn [768][2304] -> wthi/wtlo [2304][768] (f16)
// ---------------------------------------------------------------------------
__global__ __launch_bounds__(256) void split_wt_kernel(
    const float* __restrict__ W, _Float16* __restrict__ wth,
    _Float16* __restrict__ wtl)
{
    __shared__ float Ws[64][65];
    const int tid = threadIdx.x;
    const int n0 = blockIdx.x * 64, k0 = blockIdx.y * 64;
    const int lr = tid >> 4, lc = (tid & 15) << 2;
    #pragma unroll
    for (int i = 0; i < 4; ++i) {
        const float4 v = *(const float4*)(W + (size_t)(k0 + lr + i * 16) * N_QKV + n0 + lc);
        Ws[lr + i * 16][lc + 0] = v.x; Ws[lr + i * 16][lc + 1] = v.y;
        Ws[lr + i * 16][lc + 2] = v.z; Ws[lr + i * 16][lc + 3] = v.w;
    }
    __syncthreads();
    const int n = tid >> 2, ks = (tid & 3) << 4;
    half8 h0, h1, l0, l1;
    #pragma unroll
    for (int j = 0; j < 8; ++j) {
        const float v = Ws[ks + j][n];
        const _Float16 hh = (_Float16)v;
        h0[j] = hh; l0[j] = (_Float16)(v - (float)hh);
    }
    #pragma unroll
    for (int j = 0; j < 8; ++j) {
        const float v = Ws[ks + 8 + j][n];
        const _Float16 hh = (_Float16)v;
        h1[j] = hh; l1[j] = (_Float16)(v - (float)hh);
    }
    const size_t dst = (size_t)(n0 + n) * C_DIM + k0 + ks;
    *(half8*)(wth + dst) = h0; *(half8*)(wth + dst + 8) = h1;
    *(half8*)(wtl + dst) = l0; *(half8*)(wtl + dst + 8) = l1;
}

// ---------------------------------------------------------------------------
// QKV GEMM via split-f16 MFMA (AhBh + AhBl + AlBh), 128m x 64n tile, BK=64.
// Epilogue: bias + l2norm + hi/lo split (q,k) or bias + V transpose (v).
// ---------------------------------------------------------------------------
__global__ __launch_bounds__(256) void gemm_qkv_kernel(
    const _Float16* __restrict__ xh, const _Float16* __restrict__ xl,
    const _Float16* __restrict__ wth, const _Float16* __restrict__ wtl,
    const float* __restrict__ bias,
    _Float16* __restrict__ qhi, _Float16* __restrict__ qlo,
    _Float16* __restrict__ khi, _Float16* __restrict__ klo,
    _Float16* __restrict__ vt)
{
    __shared__ __align__(16) _Float16 AH[128 * 64];
    __shared__ __align__(16) _Float16 AL[128 * 64];
    __shared__ __align__(16) _Float16 BH[64 * 64];
    __shared__ __align__(16) _Float16 BL[64 * 64];
    const int tid = threadIdx.x;
    const int wv = tid >> 6, lane = tid & 63;
    const int fm = lane & 15, fg = lane >> 4;
    const int lrow = lane >> 3;
    const int lcs  = (lane & 7) ^ (lrow & 7);
    const int bx = blockIdx.x;
    const int m0 = blockIdx.y * 128;

    auto dma_chunk = [&](int c) {
        const int kc0 = c * 64;
        #pragma unroll
        for (int i = 0; i < 12; ++i) {
            const int qidx = wv * 12 + i;
            if (qidx < 16) {
                const int rg = qidx;
                GLDS(xh + (size_t)(m0 + rg * 8 + lrow) * C_DIM + kc0 + lcs * 8, &AH[rg * 512]);
            } else if (qidx < 32) {
                const int rg = qidx - 16;
                GLDS(xl + (size_t)(m0 + rg * 8 + lrow) * C_DIM + kc0 + lcs * 8, &AL[rg * 512]);
            } else if (qidx < 40) {
                const int rg = qidx - 32;
                GLDS(wth + (size_t)(bx * 64 + rg * 8 + lrow) * C_DIM + kc0 + lcs * 8, &BH[rg * 512]);
            } else {
                const int rg = qidx - 40;
                GLDS(wtl + (size_t)(bx * 64 + rg * 8 + lrow) * C_DIM + kc0 + lcs * 8, &BL[rg * 512]);
            }
        }
    };

    f32x4 acc[2][4];
    #pragma unroll
    for (int mt = 0; mt < 2; ++mt)
        #pragma unroll
        for (int ct = 0; ct < 4; ++ct) acc[mt][ct] = (f32x4){0.f, 0.f, 0.f, 0.f};

    const int swz = fm & 7;
    dma_chunk(0);
    #pragma unroll 1
    for (int c = 0; c < C_DIM / 64; ++c) {
        __syncthreads();
        half8 ah[2][2], al[2][2], bh[4][2], bl[4][2];
        #pragma unroll
        for (int mt = 0; mt < 2; ++mt) {
            const int rb = (wv * 32 + mt * 16 + fm) * 64;
            #pragma unroll
            for (int kc = 0; kc < 2; ++kc) {
                const int cb = ((kc * 4 + fg) ^ swz) * 8;
                ah[mt][kc] = *(const half8*)&AH[rb + cb];
                al[mt][kc] = *(const half8*)&AL[rb + cb];
            }
        }
        #pragma unroll
        for (int ct = 0; ct < 4; ++ct) {
            const int rb = (ct * 16 + fm) * 64;
            #pragma unroll
            for (int kc = 0; kc < 2; ++kc) {
                const int cb = ((kc * 4 + fg) ^ swz) * 8;
                bh[ct][kc] = *(const half8*)&BH[rb + cb];
                bl[ct][kc] = *(const half8*)&BL[rb + cb];
            }
        }
        __syncthreads();
        if (c + 1 < C_DIM / 64) dma_chunk(c + 1);
        #pragma unroll
        for (int mt = 0; mt < 2; ++mt)
            #pragma unroll
            for (int ct = 0; ct < 4; ++ct)
                #pragma unroll
                for (int kc = 0; kc < 2; ++kc) {
                    acc[mt][ct] = __builtin_amdgcn_mfma_f32_16x16x32_f16(ah[mt][kc], bh[ct][kc], acc[mt][ct], 0, 0, 0);
                    acc[mt][ct] = __builtin_amdgcn_mfma_f32_16x16x32_f16(ah[mt][kc], bl[ct][kc], acc[mt][ct], 0, 0, 0);
                    acc[mt][ct] = __builtin_amdgcn_mfma_f32_16x16x32_f16(al[mt][kc], bh[ct][kc], acc[mt][ct], 0, 0, 0);
                }
    }

    const int sec = bx / 12, h = bx % 12;
    const size_t hb = (size_t)h * HT;
    float bb[4];
    #pragma unroll
    for (int ct = 0; ct < 4; ++ct) bb[ct] = bias[bx * 64 + ct * 16 + fm];

    if (sec < 2) {
        _Float16* dh = (sec == 0) ? qhi : khi;
        _Float16* dl = (sec == 0) ? qlo : klo;
        #pragma unroll
        for (int mt = 0; mt < 2; ++mt)
            #pragma unroll
            for (int r = 0; r < 4; ++r) {
                float o[4];
                float ss = 0.f;
                #pragma unroll
                for (int ct = 0; ct < 4; ++ct) {
                    o[ct] = acc[mt][ct][r] + bb[ct];
                    ss += o[ct] * o[ct];
                }
                #pragma unroll
                for (int mk = 1; mk < 16; mk <<= 1) ss += __shfl_xor(ss, mk, 16);
                const float invn = 1.0f / fmaxf(sqrtf(ss), 1e-12f);
                const int t = m0 + wv * 32 + mt * 16 + fg * 4 + r;
                const size_t rb = hb + (size_t)t * HD;
                #pragma unroll
                for (int ct = 0; ct < 4; ++ct) {
                    const float v = o[ct] * invn;
                    const _Float16 vh = (_Float16)v;
                    dh[rb + ct * 16 + fm] = vh;
                    dl[rb + ct * 16 + fm] = (_Float16)(v - (float)vh);
                }
            }
    } else {
        #pragma unroll
        for (int mt = 0; mt < 2; ++mt) {
            const int t0 = m0 + wv * 32 + mt * 16 + fg * 4;
            #pragma unroll
            for (int ct = 0; ct < 4; ++ct) {
                half4 pk;
                #pragma unroll
                for (int r = 0; r < 4; ++r) pk[r] = (_Float16)(acc[mt][ct][r] + bb[ct]);
                *(half4*)(vt + hb + (size_t)(ct * 16 + fm) * T_SEQ + t0) = pk;
            }
        }
    }
}

// ---------------------------------------------------------------------------
// KSP: per head, exclusive prefix over 32-key tiles of Kn = khi+klo.
// ksphi/ksplo [h][t32=128][d=64], split f16. 12 blocks x 1024 threads.
// ---------------------------------------------------------------------------
__global__ __launch_bounds__(1024) void ksp_kernel(
    const _Float16* __restrict__ khi, const _Float16* __restrict__ klo,
    _Float16* __restrict__ ksphi, _Float16* __restrict__ ksplo)
{
    __shared__ float TS[128][64];
    const int h = blockIdx.x;
    const int d = threadIdx.x & 63, seg = threadIdx.x >> 6;   // 16 segs x 8 tiles
    const _Float16* bh = khi + (size_t)h * HT;
    const _Float16* bl = klo + (size_t)h * HT;
    #pragma unroll 1
    for (int j = 0; j < 8; ++j) {
        const int kt = seg * 8 + j;
        float s = 0.f;
        #pragma unroll 4
        for (int k = 0; k < 32; ++k) {
            const size_t key = (size_t)kt * 32 + k;
            s += (float)bh[key * HD + d] + (float)bl[key * HD + d];
        }
        TS[kt][d] = s;
    }
    __syncthreads();
    if (threadIdx.x < 64) {
        float cum = 0.f;
        #pragma unroll 1
        for (int kt = 0; kt < 128; ++kt) {
            const _Float16 hi = (_Float16)cum;
            const size_t o = ((size_t)h * 128 + kt) * 64 + d;
            ksphi[o] = hi;
            ksplo[o] = (_Float16)(cum - (float)hi);
            cum += TS[kt][d];
        }
    }
}

// ---------------------------------------------------------------------------
// Fused attention, low-register variant for 3 waves/SIMD occupancy.
// Wave (qh = wv>>1, kp = wv&1): q-rows [qh*32, qh*32+32), key-tiles
// t32 = 2*it+kp, it = 0..63. Wave-private K staging via swizzled
// global_load_lds, NO barriers until epilogue.
//   base[q][t32] = q.KSP recomputed per 8-iter group (12 MFMA / group)
//   S^T = K.Q^T via 3x split-f16 MFMA; scan: in-lane chain + 2x shfl_xor
//   att*2^-5 -> f16 -> wave-private P2 -> A-frag -> PV (K=32) MFMA
//   Epilogue: kp=0 writes YR, kp=1 adds (q-halves disjoint), store.
// ---------------------------------------------------------------------------
__global__ __launch_bounds__(256, 3) void attn_kernel(
    const _Float16* __restrict__ qhi, const _Float16* __restrict__ qlo,
    const _Float16* __restrict__ khi, const _Float16* __restrict__ klo,
    const _Float16* __restrict__ vt,
    const _Float16* __restrict__ ksphi, const _Float16* __restrict__ ksplo,
    _Float16* __restrict__ ylin)
{
    // [0, 32768): per-wave K staging (wv*8192B: hi 4KB + lo 4KB), swizzled
    // [32768, 43008): per-wave P2 (2 subs x 16 rows x 40 halfs = 2560 B)
    // epilogue: [0, 16896) reused as f32 YR (stride 66)
    __shared__ __align__(16) unsigned char SMEM[43008];
    const int tid = threadIdx.x;
    const int wv = tid >> 6, lane = tid & 63;
    const int fm = lane & 15, fg = lane >> 4;
    const int qh = wv >> 1, kp = wv & 1;
    const int h = blockIdx.y, qt = blockIdx.x;
    const size_t hb = (size_t)h * HT;

    _Float16* KSw = (_Float16*)SMEM + (size_t)wv * 4096;
    _Float16* P2w = (_Float16*)(SMEM + 32768) + (size_t)wv * (32 * 40);

    auto dma_k = [&](int key0) {
        const int r8 = lane >> 3;
        const int sc = (lane & 7) ^ (r8 & 7);
        const size_t srow = hb + (size_t)key0 * HD + sc * 8;
        _Float16* dl = KSw + 2048;
        #pragma unroll
        for (int i = 0; i < 4; ++i) {
            GLDS(khi + srow + (size_t)(i * 8 + r8) * HD, KSw + i * 512);
            GLDS(klo + srow + (size_t)(i * 8 + r8) * HD, dl  + i * 512);
        }
    };
    dma_k(kp * 32);   // tile for it=0

    // Q frags: 2 subs (rows qt*64 + qh*32 + s*16 + fm), hi/lo planes
    half8 qf[2][2][2];   // [sub][plane][kc]
    #pragma unroll
    for (int s = 0; s < 2; ++s)
        #pragma unroll
        for (int kc = 0; kc < 2; ++kc) {
            const size_t off = hb + (size_t)(qt * 64 + qh * 32 + s * 16 + fm) * HD
                             + kc * 32 + fg * 8;
            qf[s][0][kc] = *(const half8*)(qhi + off);
            qf[s][1][kc] = *(const half8*)(qlo + off);
        }

    f32x4 yacc[2][4];
    #pragma unroll
    for (int s = 0; s < 2; ++s)
        #pragma unroll
        for (int ct = 0; ct < 4; ++ct) yacc[s][ct] = (f32x4){0.f, 0.f, 0.f, 0.f};

    const int swz = fm & 7;
    float bsv[2][2];   // [sub][ri]: base for t32 = kr*16 + fg*4 + 2*ri + kp

    #pragma unroll 1
    for (int it = 0; it < 64; ++it) {
        if ((it & 7) == 0) {
            // recompute base values for t32 group kr = it>>3
            const int kr = it >> 3;
            const _Float16* sh = ksphi + (size_t)h * 8192 + (size_t)(kr * 16 + fm) * 64;
            const _Float16* sl = ksplo + (size_t)h * 8192 + (size_t)(kr * 16 + fm) * 64;
            half8 kh_[2], kl_[2];
            #pragma unroll
            for (int kc = 0; kc < 2; ++kc) {
                kh_[kc] = *(const half8*)(sh + kc * 32 + fg * 8);
                kl_[kc] = *(const half8*)(sl + kc * 32 + fg * 8);
            }
            #pragma unroll
            for (int s = 0; s < 2; ++s) {
                f32x4 b = (f32x4){0.f, 0.f, 0.f, 0.f};
                #pragma unroll
                for (int kc = 0; kc < 2; ++kc) {
                    b = __builtin_amdgcn_mfma_f32_16x16x32_f16(kh_[kc], qf[s][0][kc], b, 0, 0, 0);
                    b = __builtin_amdgcn_mfma_f32_16x16x32_f16(kh_[kc], qf[s][1][kc], b, 0, 0, 0);
                    b = __builtin_amdgcn_mfma_f32_16x16x32_f16(kl_[kc], qf[s][0][kc], b, 0, 0, 0);
                }
                bsv[s][0] = kp ? b[1] : b[0];
                bsv[s][1] = kp ? b[3] : b[2];
            }
        }
        const int key0 = (2 * it + kp) * 32;

        __builtin_amdgcn_s_waitcnt(WAIT_VM0);   // staged K(it) landed

        // K frags from wave-private staging
        half8 ka[2][2], klr[2][2];
        #pragma unroll
        for (int kr2 = 0; kr2 < 2; ++kr2)
            #pragma unroll
            for (int kc = 0; kc < 2; ++kc) {
                const int off = (kr2 * 16 + fm) * 64 + (((kc * 4 + fg) ^ swz) * 8);
                ka[kr2][kc]  = *(const half8*)(KSw + off);
                klr[kr2][kc] = *(const half8*)(KSw + 2048 + off);
            }
        // V frags direct from global (shared by both subs; in flight over S+scan)
        half8 vfr[4];
        #pragma unroll
        for (int ct = 0; ct < 4; ++ct)
            vfr[ct] = *(const half8*)(vt + hb + (size_t)(ct * 16 + fm) * T_SEQ
                                      + key0 + fg * 8);
        __builtin_amdgcn_s_waitcnt(WAIT_LGKM0);  // staged reads retired
        if (it + 1 < 64) dma_k((2 * (it + 1) + kp) * 32);   // overlaps compute

        // per-iter base broadcast: value lives in lanes fg'=(it>>1)&3, reg 2*ri+kp
        const int ri = it & 1, fgp = (it >> 1) & 3;
        const float b0 = ri ? bsv[0][1] : bsv[0][0];
        const float b1 = ri ? bsv[1][1] : bsv[1][0];
        float bsel[2];
        bsel[0] = __shfl(b0, fgp * 16 + fm, 64);
        bsel[1] = __shfl(b1, fgp * 16 + fm, 64);

        #pragma unroll
        for (int s = 0; s < 2; ++s) {
            f32x4 sacc[2];
            sacc[0] = (f32x4){0.f, 0.f, 0.f, 0.f};
            sacc[1] = (f32x4){0.f, 0.f, 0.f, 0.f};
            #pragma unroll
            for (int kr2 = 0; kr2 < 2; ++kr2)
                #pragma unroll
                for (int kc = 0; kc < 2; ++kc) {
                    sacc[kr2] = __builtin_amdgcn_mfma_f32_16x16x32_f16(ka[kr2][kc],  qf[s][0][kc], sacc[kr2], 0, 0, 0);
                    sacc[kr2] = __builtin_amdgcn_mfma_f32_16x16x32_f16(ka[kr2][kc],  qf[s][1][kc], sacc[kr2], 0, 0, 0);
                    sacc[kr2] = __builtin_amdgcn_mfma_f32_16x16x32_f16(klr[kr2][kc], qf[s][0][kc], sacc[kr2], 0, 0, 0);
                }
            float loc = bsel[s];
            #pragma unroll
            for (int kr2 = 0; kr2 < 2; ++kr2) {
                const float s0 = sacc[kr2][0], s1 = sacc[kr2][1];
                const float s2 = sacc[kr2][2], s3 = sacc[kr2][3];
                const float p1 = s0 + s1, p2 = p1 + s2, p3 = p2 + s3;
                const float u1 = __shfl_xor(p3, 16, 64);
                const float pair = p3 + u1;
                const float u2 = __shfl_xor(pair, 32, 64);
                const float tot16 = pair + u2;
                const float pref = ((fg & 1) ? u1 : 0.0f) + ((fg & 2) ? u2 : 0.0f);
                const float base = loc + pref;
                loc += tot16;
                const float a0 = s0 * __builtin_amdgcn_rcpf(fmaxf(base + s0, 1e-6f));
                const float a1 = s1 * __builtin_amdgcn_rcpf(fmaxf(base + p1, 1e-6f));
                const float a2 = s2 * __builtin_amdgcn_rcpf(fmaxf(base + p2, 1e-6f));
                const float a3 = s3 * __builtin_amdgcn_rcpf(fmaxf(base + p3, 1e-6f));
                half4 pk = {(_Float16)(a0 * 0.03125f), (_Float16)(a1 * 0.03125f),
                            (_Float16)(a2 * 0.03125f), (_Float16)(a3 * 0.03125f)};
                *(half4*)(P2w + (s * 16 + fm) * 40 + kr2 * 16 + fg * 4) = pk;
            }
            // PV: A-frag from wave-private P2, K=32
            const half8 ap = *(const half8*)(P2w + (s * 16 + fm) * 40 + fg * 8);
            #pragma unroll
            for (int ct = 0; ct < 4; ++ct)
                yacc[s][ct] = __builtin_amdgcn_mfma_f32_16x16x32_f16(ap, vfr[ct], yacc[s][ct], 0, 0, 0);
        }
    }

    // cross-wave (kp pair) Y reduction through LDS; q-halves disjoint rows
    __syncthreads();
    float* YR = (float*)SMEM;
    if (kp == 0) {
        #pragma unroll
        for (int s = 0; s < 2; ++s)
            #pragma unroll
            for (int ct = 0; ct < 4; ++ct)
                #pragma unroll
                for (int r = 0; r < 4; ++r)
                    YR[(qh * 32 + s * 16 + fg * 4 + r) * 66 + ct * 16 + fm] = yacc[s][ct][r];
    }
    __syncthreads();
    if (kp == 1) {
        #pragma unroll
        for (int s = 0; s < 2; ++s)
            #pragma unroll
            for (int ct = 0; ct < 4; ++ct)
                #pragma unroll
                for (int r = 0; r < 4; ++r)
                    YR[(qh * 32 + s * 16 + fg * 4 + r) * 66 + ct * 16 + fm] += yacc[s][ct][r];
    }
    __syncthreads();
    // write ylin f16 = y * 2^-12 (acc holds y*2^-5 -> scale 2^-7)
    const int tq = tid >> 2, c0 = (tid & 3) * 16;
    const float* yr = &YR[tq * 66 + c0];
    half8 o0, o1;
    #pragma unroll
    for (int j = 0; j < 8; ++j) {
        o0[j] = (_Float16)(yr[j]     * 0.0078125f);
        o1[j] = (_Float16)(yr[8 + j] * 0.0078125f);
    }
    _Float16* dst = ylin + (size_t)(qt * 64 + tq) * C_DIM + h * HD + c0;
    *(half8*)dst       = o0;
    *(half8*)(dst + 8) = o1;
}

// ---------------------------------------------------------------------------
// Proj GEMM via f16 MFMA: ylin(f16, *2^-12)[4096,768] @ Wp[768,768] -> out fp32
// ---------------------------------------------------------------------------
__global__ __launch_bounds__(256) void gemm_proj_kernel(
    const _Float16* __restrict__ A, const float* __restrict__ W,
    const float* __restrict__ bias, float* __restrict__ out)
{
    __shared__ _Float16 As[64][72];
    __shared__ _Float16 Bt[64][72];
    typedef _Float16 half2v __attribute__((ext_vector_type(2)));
    const int tid = threadIdx.x;
    const int w = tid >> 6, lane = tid & 63;
    const int m = lane & 15, g = lane >> 4;
    const int row0 = blockIdx.x << 6, col0 = blockIdx.y << 6;
    const int ar = tid >> 3, ac8 = (tid & 7) << 3;
    const int bn0 = (tid & 15) << 2, bpv = tid >> 4;
    f32x4 acc[4];
    #pragma unroll
    for (int ct = 0; ct < 4; ++ct) acc[ct] = (f32x4){0.f, 0.f, 0.f, 0.f};

    for (int kt = 0; kt < C_DIM; kt += 64) {
        half8 av0 = *(const half8*)(A + (size_t)(row0 + ar)      * C_DIM + kt + ac8);
        half8 av1 = *(const half8*)(A + (size_t)(row0 + ar + 32) * C_DIM + kt + ac8);
        float4 w0[2], w1[2];
        #pragma unroll
        for (int i = 0; i < 2; ++i) {
            const int k = kt + 2 * (bpv + 16 * i);
            w0[i] = *(const float4*)(W + (size_t)k       * C_DIM + col0 + bn0);
            w1[i] = *(const float4*)(W + (size_t)(k + 1) * C_DIM + col0 + bn0);
        }
        __syncthreads();
        *(half8*)&As[ar][ac8]      = av0;
        *(half8*)&As[ar + 32][ac8] = av1;
        #pragma unroll
        for (int i = 0; i < 2; ++i) {
            const int p = bpv + 16 * i;
            const float a_[4] = {w0[i].x, w0[i].y, w0[i].z, w0[i].w};
            const float b_[4] = {w1[i].x, w1[i].y, w1[i].z, w1[i].w};
            #pragma unroll
            for (int u = 0; u < 4; ++u) {
                half2v pk = {(_Float16)a_[u], (_Float16)b_[u]};
                *(half2v*)&Bt[bn0 + u][2 * p] = pk;
            }
        }
        __syncthreads();
        #pragma unroll
        for (int kc = 0; kc < 2; ++kc) {
            const half8 a = *(half8*)&As[w * 16 + m][kc * 32 + g * 8];
            #pragma unroll
            for (int ct = 0; ct < 4; ++ct) {
                const half8 b = *(half8*)&Bt[ct * 16 + m][kc * 32 + g * 8];
                acc[ct] = __builtin_amdgcn_mfma_f32_16x16x32_f16(a, b, acc[ct], 0, 0, 0);
            }
        }
    }
    #pragma unroll
    for (int ct = 0; ct < 4; ++ct)
        #pragma unroll
        for (int r = 0; r < 4; ++r) {
            const int t = row0 + w * 16 + g * 4 + r;
            const int n = col0 + ct * 16 + m;
            out[(size_t)t * C_DIM + n] = acc[ct][r] * 4096.0f + bias[n];
        }
}

extern "C" void kernel_launch(void* const* d_in, const int* in_sizes, int n_in,
                              void* d_out, int out_size, void* d_ws, size_t ws_size,
                              hipStream_t stream)
{
    const float* x      = (const float*)d_in[0];
    const float* w_attn = (const float*)d_in[1];
    const float* b_attn = (const float*)d_in[2];
    const float* w_proj = (const float*)d_in[3];
    const float* b_proj = (const float*)d_in[4];
    float* out = (float*)d_out;

    const size_t perQK = (size_t)H_NUM * HT;      // 3,145,728
    const size_t perX  = (size_t)T_SEQ * C_DIM;   // 3,145,728
    const size_t perW  = (size_t)N_QKV * C_DIM;   // 1,769,472
    _Float16* base = (_Float16*)d_ws;
    _Float16* xhi  = base;
    _Float16* xlo  = xhi + perX;
    _Float16* wthi = xlo + perX;
    _Float16* wtlo = wthi + perW;
    _Float16* qhi  = wtlo + perW;
    _Float16* qlo  = qhi + perQK;
    _Float16* khi  = qlo + perQK;
    _Float16* klo  = khi + perQK;
    _Float16* vtp  = klo + perQK;
    _Float16* ylin = xhi;                          // xhi dead after qkv
    _Float16* ksph = xlo;                          // xlo dead after qkv
    _Float16* kspl = xlo + (size_t)H_NUM * 128 * 64;

    split_x_kernel<<<(perX / 4 + 255) / 256, 256, 0, stream>>>(x, xhi, xlo, perX / 4);
    split_wt_kernel<<<dim3(N_QKV / 64, C_DIM / 64), 256, 0, stream>>>(w_attn, wthi, wtlo);
    gemm_qkv_kernel<<<dim3(N_QKV / 64, T_SEQ / 128), 256, 0, stream>>>(
        xhi, xlo, wthi, wtlo, b_attn, qhi, qlo, khi, klo, vtp);
    ksp_kernel<<<H_NUM, 1024, 0, stream>>>(khi, klo, ksph, kspl);
    attn_kernel<<<dim3(T_SEQ / 64, H_NUM), 256, 0, stream>>>(
        qhi, qlo, khi, klo, vtp, ksph, kspl, ylin);
    gemm_proj_kernel<<<dim3(T_SEQ / 64, C_DIM / 64), 256, 0, stream>>>(
        ylin, w_proj, b_proj, out);
}